// Round 1
// baseline (184.263 us; speedup 1.0000x reference)
//
#include <hip/hip_runtime.h>

#define H 768
#define SEQLEN 512
#define NBATCH 4
#define NSPAN 128
#define MTOT (NBATCH * NSPAN)   // 512

// 16-FMA micro-tile update from LDS tiles As[k][m], Bs[k][n]
#define GEMM_FMA(kk) do {                                                      \
    const float4 a_ = *(const float4*)&As[kk][m0];                             \
    const float4 b_ = *(const float4*)&Bs[kk][n0];                             \
    const float av_[4] = {a_.x, a_.y, a_.z, a_.w};                             \
    const float bv_[4] = {b_.x, b_.y, b_.z, b_.w};                             \
    _Pragma("unroll") for (int mi_ = 0; mi_ < 4; ++mi_)                        \
      _Pragma("unroll") for (int ni_ = 0; ni_ < 4; ++ni_)                      \
        acc[mi_][ni_] = fmaf(av_[mi_], bv_[ni_], acc[mi_][ni_]);               \
} while (0)

// ---------------------------------------------------------------------------
// K1: SE = gather(seq, starts) @ W_start + b_start   (z = 0)
//     EE = gather(seq, ends)   @ W_end   + b_end     (z = 1)
// ---------------------------------------------------------------------------
__global__ __launch_bounds__(256) void k_se_ee(
    const float* __restrict__ seq,
    const int* __restrict__ starts, const int* __restrict__ ends,
    const float* __restrict__ Ws, const float* __restrict__ bs,
    const float* __restrict__ We, const float* __restrict__ be,
    float* __restrict__ SE, float* __restrict__ EE)
{
    const int z = blockIdx.z;
    const int* __restrict__ idx  = z ? ends : starts;
    const float* __restrict__ W    = z ? We : Ws;
    const float* __restrict__ bias = z ? be : bs;
    float* __restrict__ out        = z ? EE : SE;

    __shared__ __align__(16) float As[32][68];
    __shared__ __align__(16) float Bs[32][64];

    const int tid = threadIdx.x;
    const int bm = blockIdx.x, bn = blockIdx.y;
    const int m0 = (tid >> 4) << 2;
    const int n0 = (tid & 15) << 2;

    float acc[4][4] = {{0.f}};

    const int sm  = tid >> 3;          // 0..31 (A staging row)
    const int skq = (tid & 7) << 2;    // 0..28 (A staging k chunk)
    const int sk  = tid >> 4;          // 0..15 (B staging row)
    const int sn0 = (tid & 15) << 2;   // 0..60 (B staging col chunk)

    const int gmA = bm * 64 + sm;
    const float* __restrict__ arow0 =
        seq + ((size_t)((gmA >> 7) * SEQLEN + idx[gmA])) * H;
    const float* __restrict__ arow1 =
        seq + ((size_t)(((gmA + 32) >> 7) * SEQLEN + idx[gmA + 32])) * H;

    for (int it = 0; it < 24; ++it) {
        const int k0 = it << 5;
        __syncthreads();
        {
            float4 v0 = *(const float4*)(arow0 + k0 + skq);
            float4 v1 = *(const float4*)(arow1 + k0 + skq);
            As[skq+0][sm] = v0.x; As[skq+1][sm] = v0.y;
            As[skq+2][sm] = v0.z; As[skq+3][sm] = v0.w;
            As[skq+0][sm+32] = v1.x; As[skq+1][sm+32] = v1.y;
            As[skq+2][sm+32] = v1.z; As[skq+3][sm+32] = v1.w;
            *(float4*)&Bs[sk][sn0] =
                *(const float4*)(W + (size_t)(k0 + sk) * H + bn*64 + sn0);
            *(float4*)&Bs[sk+16][sn0] =
                *(const float4*)(W + (size_t)(k0 + sk + 16) * H + bn*64 + sn0);
        }
        __syncthreads();
        #pragma unroll
        for (int k = 0; k < 32; ++k) GEMM_FMA(k);
    }

    const float4 bv = *(const float4*)(bias + bn*64 + n0);
    #pragma unroll
    for (int mi = 0; mi < 4; ++mi) {
        float4 st = { acc[mi][0]+bv.x, acc[mi][1]+bv.y,
                      acc[mi][2]+bv.z, acc[mi][3]+bv.w };
        *(float4*)(out + (size_t)(bm*64 + m0 + mi) * H + bn*64 + n0) = st;
    }
}

// ---------------------------------------------------------------------------
// K2: SR = [SE | EE | width_emb[w]] @ W_out + b_out   (K = 1566 = 768+768+30)
// ---------------------------------------------------------------------------
__global__ __launch_bounds__(256) void k_sr(
    const float* __restrict__ SE, const float* __restrict__ EE,
    const int* __restrict__ starts, const int* __restrict__ ends,
    const float* __restrict__ wemb, const float* __restrict__ Wout,
    const float* __restrict__ bout, float* __restrict__ SR)
{
    __shared__ __align__(16) float As[32][68];
    __shared__ __align__(16) float Bs[32][64];

    const int tid = threadIdx.x;
    const int bm = blockIdx.x, bn = blockIdx.y;
    const int m0 = (tid >> 4) << 2;
    const int n0 = (tid & 15) << 2;

    float acc[4][4] = {{0.f}};

    const int sm  = tid >> 3;
    const int skq = (tid & 7) << 2;
    const int sk  = tid >> 4;
    const int sn0 = (tid & 15) << 2;
    const int gm0 = bm * 64 + sm, gm1 = gm0 + 32;

    for (int it = 0; it < 48; ++it) {
        const float* __restrict__ Ab = (it < 24) ? SE : EE;
        const int k0  = (it < 24) ? (it << 5) : ((it - 24) << 5);
        const int gk0 = it << 5;   // row into W_out
        __syncthreads();
        {
            float4 v0 = *(const float4*)(Ab + (size_t)gm0 * H + k0 + skq);
            float4 v1 = *(const float4*)(Ab + (size_t)gm1 * H + k0 + skq);
            As[skq+0][sm] = v0.x; As[skq+1][sm] = v0.y;
            As[skq+2][sm] = v0.z; As[skq+3][sm] = v0.w;
            As[skq+0][sm+32] = v1.x; As[skq+1][sm+32] = v1.y;
            As[skq+2][sm+32] = v1.z; As[skq+3][sm+32] = v1.w;
            *(float4*)&Bs[sk][sn0] =
                *(const float4*)(Wout + (size_t)(gk0 + sk) * H + bn*64 + sn0);
            *(float4*)&Bs[sk+16][sn0] =
                *(const float4*)(Wout + (size_t)(gk0 + sk + 16) * H + bn*64 + sn0);
        }
        __syncthreads();
        #pragma unroll
        for (int k = 0; k < 32; ++k) GEMM_FMA(k);
    }

    // tail: K = 30 width-embedding block
    __syncthreads();
    for (int t = tid; t < 64 * 30; t += 256) {
        int m = t / 30, k = t % 30;
        int gm = bm * 64 + m;
        int w = ends[gm] - starts[gm];
        w = w < 0 ? 0 : (w > 10 ? 10 : w);
        As[k][m] = wemb[w * 30 + k];
    }
    for (int t = tid; t < 30 * 64; t += 256) {
        int k = t >> 6, n = t & 63;
        Bs[k][n] = Wout[(size_t)(1536 + k) * H + bn*64 + n];
    }
    __syncthreads();
    #pragma unroll
    for (int k = 0; k < 30; ++k) GEMM_FMA(k);

    const float4 bv = *(const float4*)(bout + bn*64 + n0);
    #pragma unroll
    for (int mi = 0; mi < 4; ++mi) {
        float4 st = { acc[mi][0]+bv.x, acc[mi][1]+bv.y,
                      acc[mi][2]+bv.z, acc[mi][3]+bv.w };
        *(float4*)(SR + (size_t)(bm*64 + m0 + mi) * H + bn*64 + n0) = st;
    }
}

// ---------------------------------------------------------------------------
// K3: z=0: AI = SR @ (Wa + Wc) + b1     (b1 folded here, not in K4)
//     z=1: BJ = SR @ (Wb - Wc)
//     z=2 (by==0 only): mention = SR @ W_ment + b_ment
// ---------------------------------------------------------------------------
__global__ __launch_bounds__(256) void k_ai_bj(
    const float* __restrict__ SR, const float* __restrict__ W1,
    const float* __restrict__ b1, const float* __restrict__ Wm,
    const float* __restrict__ bment,
    float* __restrict__ AI, float* __restrict__ BJ,
    float* __restrict__ mention)
{
    const int z = blockIdx.z;
    const int tid = threadIdx.x;

    if (z == 2) {
        if (blockIdx.y != 0) return;
        const int wave = tid >> 6, lane = tid & 63;
        const int row_base = blockIdx.x * 64 + wave * 16;
        for (int rr = 0; rr < 16; ++rr) {
            const int row = row_base + rr;
            float p = 0.f;
            for (int k = lane; k < H; k += 64)
                p = fmaf(SR[(size_t)row * H + k], Wm[k], p);
            #pragma unroll
            for (int off = 32; off; off >>= 1) p += __shfl_down(p, off);
            if (lane == 0) mention[row] = p + bment[0];
        }
        return;
    }

    __shared__ __align__(16) float As[32][68];
    __shared__ __align__(16) float Bs[32][64];

    const int bm = blockIdx.x, bn = blockIdx.y;
    const int m0 = (tid >> 4) << 2;
    const int n0 = (tid & 15) << 2;

    float acc[4][4] = {{0.f}};

    const int sm  = tid >> 3;
    const int skq = (tid & 7) << 2;
    const int sk  = tid >> 4;
    const int sn0 = (tid & 15) << 2;
    const int gm0 = bm * 64 + sm, gm1 = gm0 + 32;

    const float sgn = z ? -1.f : 1.f;
    const float* __restrict__ W1ab = W1 + (size_t)(z ? 768 : 0) * H;
    const float* __restrict__ W1c  = W1 + (size_t)1536 * H;
    float* __restrict__ out = z ? BJ : AI;

    for (int it = 0; it < 24; ++it) {
        const int k0 = it << 5;
        __syncthreads();
        {
            float4 v0 = *(const float4*)(SR + (size_t)gm0 * H + k0 + skq);
            float4 v1 = *(const float4*)(SR + (size_t)gm1 * H + k0 + skq);
            As[skq+0][sm] = v0.x; As[skq+1][sm] = v0.y;
            As[skq+2][sm] = v0.z; As[skq+3][sm] = v0.w;
            As[skq+0][sm+32] = v1.x; As[skq+1][sm+32] = v1.y;
            As[skq+2][sm+32] = v1.z; As[skq+3][sm+32] = v1.w;
            float4 u0 = *(const float4*)(W1ab + (size_t)(k0 + sk) * H + bn*64 + sn0);
            float4 c0 = *(const float4*)(W1c  + (size_t)(k0 + sk) * H + bn*64 + sn0);
            float4 u1 = *(const float4*)(W1ab + (size_t)(k0 + sk + 16) * H + bn*64 + sn0);
            float4 c1 = *(const float4*)(W1c  + (size_t)(k0 + sk + 16) * H + bn*64 + sn0);
            float4 r0 = { fmaf(sgn, c0.x, u0.x), fmaf(sgn, c0.y, u0.y),
                          fmaf(sgn, c0.z, u0.z), fmaf(sgn, c0.w, u0.w) };
            float4 r1 = { fmaf(sgn, c1.x, u1.x), fmaf(sgn, c1.y, u1.y),
                          fmaf(sgn, c1.z, u1.z), fmaf(sgn, c1.w, u1.w) };
            *(float4*)&Bs[sk][sn0]    = r0;
            *(float4*)&Bs[sk+16][sn0] = r1;
        }
        __syncthreads();
        #pragma unroll
        for (int k = 0; k < 32; ++k) GEMM_FMA(k);
    }

    float4 bv = {0.f, 0.f, 0.f, 0.f};
    if (z == 0) bv = *(const float4*)(b1 + bn*64 + n0);
    #pragma unroll
    for (int mi = 0; mi < 4; ++mi) {
        float4 st = { acc[mi][0]+bv.x, acc[mi][1]+bv.y,
                      acc[mi][2]+bv.z, acc[mi][3]+bv.w };
        *(float4*)(out + (size_t)(bm*64 + m0 + mi) * H + bn*64 + n0) = st;
    }
}

// ---------------------------------------------------------------------------
// K4: pairwise[b,i,j] = (j < i) ? sum_h relu(AI[b,i,h] + BJ[b,j,h]) * W2[h] + b2 : 0
//     (b1 already folded into AI). 16x16 pair tile per block.
// ---------------------------------------------------------------------------
__global__ __launch_bounds__(256) void k_pair(
    const float* __restrict__ AI, const float* __restrict__ BJ,
    const float* __restrict__ W2, const float* __restrict__ b2,
    float* __restrict__ pair)
{
    const int tid = threadIdx.x;
    const int tx = tid & 15, ty = tid >> 4;
    const int bx = blockIdx.x, by = blockIdx.y, bz = blockIdx.z;
    const int i = by * 16 + ty, j = bx * 16 + tx;
    float* outp = pair + ((size_t)bz * NSPAN + i) * NSPAN + j;

    if (bx > by) { *outp = 0.f; return; }   // strictly-upper tile: all zero

    __shared__ __align__(16) float Ais[16][68];
    __shared__ __align__(16) float Bjs[16][68];
    __shared__ __align__(16) float w2s[768];
    for (int t = tid; t < 768; t += 256) w2s[t] = W2[t];

    const int sr = tid >> 4, sc = (tid & 15) << 2;
    float acc = 0.f;

    for (int ch = 0; ch < 12; ++ch) {
        __syncthreads();
        *(float4*)&Ais[sr][sc] =
            *(const float4*)(AI + ((size_t)bz * NSPAN + by*16 + sr) * H + ch*64 + sc);
        *(float4*)&Bjs[sr][sc] =
            *(const float4*)(BJ + ((size_t)bz * NSPAN + bx*16 + sr) * H + ch*64 + sc);
        __syncthreads();
        #pragma unroll
        for (int hq = 0; hq < 16; ++hq) {
            float4 a = *(const float4*)&Ais[ty][hq << 2];
            float4 b = *(const float4*)&Bjs[tx][hq << 2];
            float4 w = *(const float4*)&w2s[ch*64 + (hq << 2)];
            acc = fmaf(fmaxf(a.x + b.x, 0.f), w.x, acc);
            acc = fmaf(fmaxf(a.y + b.y, 0.f), w.y, acc);
            acc = fmaf(fmaxf(a.z + b.z, 0.f), w.z, acc);
            acc = fmaf(fmaxf(a.w + b.w, 0.f), w.w, acc);
        }
    }
    *outp = (j < i) ? (acc + b2[0]) : 0.f;
}

// ---------------------------------------------------------------------------
extern "C" void kernel_launch(void* const* d_in, const int* in_sizes, int n_in,
                              void* d_out, int out_size, void* d_ws, size_t ws_size,
                              hipStream_t stream)
{
    const float* seq    = (const float*)d_in[0];
    const int*   starts = (const int*)  d_in[1];
    const int*   ends   = (const int*)  d_in[2];
    const float* Ws     = (const float*)d_in[3];
    const float* bs     = (const float*)d_in[4];
    const float* We     = (const float*)d_in[5];
    const float* be     = (const float*)d_in[6];
    const float* wemb   = (const float*)d_in[7];
    const float* Wout   = (const float*)d_in[8];
    const float* bout   = (const float*)d_in[9];
    const float* Wm     = (const float*)d_in[10];
    const float* bment  = (const float*)d_in[11];
    const float* W1     = (const float*)d_in[12];
    const float* b1     = (const float*)d_in[13];
    const float* W2     = (const float*)d_in[14];
    const float* b2     = (const float*)d_in[15];

    float* ws  = (float*)d_ws;
    float* SE  = ws;                      // 512*768
    float* EE  = ws + 393216;             // 512*768
    float* SR  = ws + 786432;             // 512*768
    float* AI  = SE;                      // reuse after K2
    float* BJ  = EE;

    float* out_mention = (float*)d_out;         // 512
    float* out_pair    = (float*)d_out + 512;   // 4*128*128

    hipLaunchKernelGGL(k_se_ee, dim3(8, 12, 2), dim3(256), 0, stream,
                       seq, starts, ends, Ws, bs, We, be, SE, EE);
    hipLaunchKernelGGL(k_sr, dim3(8, 12, 1), dim3(256), 0, stream,
                       SE, EE, starts, ends, wemb, Wout, bout, SR);
    hipLaunchKernelGGL(k_ai_bj, dim3(8, 12, 3), dim3(256), 0, stream,
                       SR, W1, b1, Wm, bment, AI, BJ, out_mention);
    hipLaunchKernelGGL(k_pair, dim3(8, 8, 4), dim3(256), 0, stream,
                       AI, BJ, W2, b2, out_pair);
}

// Round 2
// 136.472 us; speedup vs baseline: 1.3502x; 1.3502x over previous
//
#include <hip/hip_runtime.h>
#include <hip/hip_bf16.h>

#define H 768
#define K2P 1568          // 768 + 768 + 32 (width padded 30->32)
#define SEQLEN 512
#define MTOT 512          // B*N rows
#define NSPAN 128

typedef __attribute__((ext_vector_type(8))) short s16x8;
typedef __attribute__((ext_vector_type(4))) float f32x4;

__device__ __forceinline__ short f2bf(float f) {
    __hip_bfloat16 h = __float2bfloat16(f);
    return *reinterpret_cast<short*>(&h);
}

__device__ __forceinline__ s16x8 cvt8(float4 v0, float4 v1) {
    s16x8 r;
    r[0] = f2bf(v0.x); r[1] = f2bf(v0.y); r[2] = f2bf(v0.z); r[3] = f2bf(v0.w);
    r[4] = f2bf(v1.x); r[5] = f2bf(v1.y); r[6] = f2bf(v1.z); r[7] = f2bf(v1.w);
    return r;
}

// ---------------------------------------------------------------------------
// P0: weight transpose+convert to bf16 [n][k], W1 combos, X_cat width columns.
// blocks: 0..575 Wt_s | 576..1151 Wt_e | 1152..1727 WtA(=Wa+Wc) |
//         1728..2303 WtB(=Wb-Wc) | 2304..3479 Wt_out | 3480..3543 Xcat wE
// ---------------------------------------------------------------------------
__global__ __launch_bounds__(256) void k_prep(
    const float* __restrict__ Ws, const float* __restrict__ We,
    const float* __restrict__ W1, const float* __restrict__ Wout,
    const float* __restrict__ wemb,
    const int* __restrict__ starts, const int* __restrict__ ends,
    short* __restrict__ Wt_s, short* __restrict__ Wt_e,
    short* __restrict__ WtA, short* __restrict__ WtB,
    short* __restrict__ Wt_out, float* __restrict__ Xcat)
{
    const int b = blockIdx.x;
    const int tid = threadIdx.x;

    if (b < 2304) {
        const int sec = b / 576;
        const int t = b % 576;
        const int kt = t / 24, nt = t % 24;
        __shared__ float tile[32][33];
        const int kk = tid >> 3;
        const int c4 = (tid & 7) << 2;
        const int srow = kt * 32 + kk, scol = nt * 32 + c4;
        float4 v;
        if (sec == 0)      v = *(const float4*)(Ws + (size_t)srow * H + scol);
        else if (sec == 1) v = *(const float4*)(We + (size_t)srow * H + scol);
        else {
            const float* base = W1 + (size_t)(sec == 2 ? 0 : H) * H;
            float4 u = *(const float4*)(base + (size_t)srow * H + scol);
            float4 c = *(const float4*)(W1 + (size_t)2 * H * H + (size_t)srow * H + scol);
            const float sg = (sec == 2) ? 1.f : -1.f;
            v = make_float4(fmaf(sg, c.x, u.x), fmaf(sg, c.y, u.y),
                            fmaf(sg, c.z, u.z), fmaf(sg, c.w, u.w));
        }
        tile[kk][c4+0] = v.x; tile[kk][c4+1] = v.y;
        tile[kk][c4+2] = v.z; tile[kk][c4+3] = v.w;
        __syncthreads();
        short* dst = sec == 0 ? Wt_s : sec == 1 ? Wt_e : sec == 2 ? WtA : WtB;
        const int nn = tid >> 3;
        short4 o;
        o.x = f2bf(tile[c4+0][nn]); o.y = f2bf(tile[c4+1][nn]);
        o.z = f2bf(tile[c4+2][nn]); o.w = f2bf(tile[c4+3][nn]);
        *(short4*)(dst + (size_t)(nt*32 + nn) * H + kt*32 + c4) = o;
    } else if (b < 3480) {
        const int t = b - 2304;
        const int nt = t / 49, kt = t % 49;
        __shared__ float tile[32][33];
        const int kk = tid >> 3;
        const int c4 = (tid & 7) << 2;
        const int srow = kt * 32 + kk, scol = nt * 32 + c4;
        float4 v = make_float4(0.f, 0.f, 0.f, 0.f);
        if (srow < 1566) v = *(const float4*)(Wout + (size_t)srow * H + scol);
        tile[kk][c4+0] = v.x; tile[kk][c4+1] = v.y;
        tile[kk][c4+2] = v.z; tile[kk][c4+3] = v.w;
        __syncthreads();
        const int nn = tid >> 3;
        short4 o;
        o.x = f2bf(tile[c4+0][nn]); o.y = f2bf(tile[c4+1][nn]);
        o.z = f2bf(tile[c4+2][nn]); o.w = f2bf(tile[c4+3][nn]);
        *(short4*)(Wt_out + (size_t)(nt*32 + nn) * K2P + kt*32 + c4) = o;
    } else {
        const int t = (b - 3480) * 256 + tid;   // 0..16383 = 512 rows x 32 cols
        const int row = t >> 5, c = t & 31;
        int w = ends[row] - starts[row];
        w = w < 0 ? 0 : (w > 10 ? 10 : w);
        Xcat[(size_t)row * K2P + 1536 + c] = (c < 30) ? wemb[w * 30 + c] : 0.f;
    }
}

// ---------------------------------------------------------------------------
// G1: X_cat[:, z*768 + n] = gather(seq, idx_z) @ Wt_z^T + bias_z
// 1 wave per block, 32x32 tile, LDS-free MFMA.
// ---------------------------------------------------------------------------
__global__ __launch_bounds__(64) void k_g1(
    const float* __restrict__ seq,
    const int* __restrict__ starts, const int* __restrict__ ends,
    const short* __restrict__ Wt_s, const short* __restrict__ Wt_e,
    const float* __restrict__ bs, const float* __restrict__ be,
    float* __restrict__ Xcat)
{
    const int z = blockIdx.z;
    const int* __restrict__ idx = z ? ends : starts;
    const short* __restrict__ Wt = z ? Wt_e : Wt_s;
    const float* __restrict__ bias = z ? be : bs;

    const int l = threadIdx.x;
    const int m0 = blockIdx.x * 32, n0 = blockIdx.y * 32;
    const int lr = l & 15, lg = l >> 4;

    const float* arow[2];
    #pragma unroll
    for (int i = 0; i < 2; ++i) {
        const int row = m0 + 16*i + lr;
        arow[i] = seq + ((size_t)((row >> 7) * SEQLEN + idx[row])) * H + lg * 8;
    }
    const short* brow[2];
    #pragma unroll
    for (int j = 0; j < 2; ++j)
        brow[j] = Wt + (size_t)(n0 + 16*j + lr) * H + lg * 8;

    f32x4 acc[2][2] = {};
    #pragma unroll 2
    for (int k0 = 0; k0 < H; k0 += 32) {
        s16x8 a[2], bf[2];
        #pragma unroll
        for (int i = 0; i < 2; ++i) {
            float4 v0 = *(const float4*)(arow[i] + k0);
            float4 v1 = *(const float4*)(arow[i] + k0 + 4);
            a[i] = cvt8(v0, v1);
        }
        #pragma unroll
        for (int j = 0; j < 2; ++j)
            bf[j] = *(const s16x8*)(brow[j] + k0);
        #pragma unroll
        for (int i = 0; i < 2; ++i)
            #pragma unroll
            for (int j = 0; j < 2; ++j)
                acc[i][j] = __builtin_amdgcn_mfma_f32_16x16x32_bf16(a[i], bf[j], acc[i][j], 0, 0, 0);
    }

    #pragma unroll
    for (int j = 0; j < 2; ++j) {
        const float bv = bias[n0 + 16*j + lr];
        const int col = z * H + n0 + 16*j + lr;
        #pragma unroll
        for (int i = 0; i < 2; ++i) {
            const int rbase = m0 + 16*i + lg*4;
            #pragma unroll
            for (int r = 0; r < 4; ++r)
                Xcat[(size_t)(rbase + r) * K2P + col] = acc[i][j][r] + bv;
        }
    }
}

// ---------------------------------------------------------------------------
// G2: SR = Xcat(fp32, K=1568) @ Wt_out^T + b_out
// ---------------------------------------------------------------------------
__global__ __launch_bounds__(64) void k_g2(
    const float* __restrict__ Xcat, const short* __restrict__ Wt_out,
    const float* __restrict__ bout, float* __restrict__ SR)
{
    const int l = threadIdx.x;
    const int m0 = blockIdx.x * 32, n0 = blockIdx.y * 32;
    const int lr = l & 15, lg = l >> 4;

    const float* arow[2];
    #pragma unroll
    for (int i = 0; i < 2; ++i)
        arow[i] = Xcat + (size_t)(m0 + 16*i + lr) * K2P + lg * 8;
    const short* brow[2];
    #pragma unroll
    for (int j = 0; j < 2; ++j)
        brow[j] = Wt_out + (size_t)(n0 + 16*j + lr) * K2P + lg * 8;

    f32x4 acc[2][2] = {};
    #pragma unroll 2
    for (int k0 = 0; k0 < K2P; k0 += 32) {
        s16x8 a[2], bf[2];
        #pragma unroll
        for (int i = 0; i < 2; ++i) {
            float4 v0 = *(const float4*)(arow[i] + k0);
            float4 v1 = *(const float4*)(arow[i] + k0 + 4);
            a[i] = cvt8(v0, v1);
        }
        #pragma unroll
        for (int j = 0; j < 2; ++j)
            bf[j] = *(const s16x8*)(brow[j] + k0);
        #pragma unroll
        for (int i = 0; i < 2; ++i)
            #pragma unroll
            for (int j = 0; j < 2; ++j)
                acc[i][j] = __builtin_amdgcn_mfma_f32_16x16x32_bf16(a[i], bf[j], acc[i][j], 0, 0, 0);
    }

    #pragma unroll
    for (int j = 0; j < 2; ++j) {
        const float bv = bout[n0 + 16*j + lr];
        const int col = n0 + 16*j + lr;
        #pragma unroll
        for (int i = 0; i < 2; ++i) {
            const int rbase = m0 + 16*i + lg*4;
            #pragma unroll
            for (int r = 0; r < 4; ++r)
                SR[(size_t)(rbase + r) * H + col] = acc[i][j][r] + bv;
        }
    }
}

// ---------------------------------------------------------------------------
// G3: z=0: AI = SR @ WtA^T + b1 ; z=1: BJ = SR @ WtB^T ;
//     z=2 (bn<12): mention += partial dot(SR, Wm) via atomics (+b_ment at bn==0)
// ---------------------------------------------------------------------------
__global__ __launch_bounds__(64) void k_g3(
    const float* __restrict__ SR, const short* __restrict__ WtA,
    const short* __restrict__ WtB, const float* __restrict__ b1,
    const float* __restrict__ Wm, const float* __restrict__ bment,
    float* __restrict__ AI, float* __restrict__ BJ, float* __restrict__ mention)
{
    const int z = blockIdx.z;
    const int l = threadIdx.x;

    if (z == 2) {
        if (blockIdx.y >= 12) return;
        const int k = blockIdx.y * 64 + l;
        const float wv = Wm[k];
        const int row0 = blockIdx.x * 32;
        const float bm_add = (blockIdx.y == 0) ? bment[0] : 0.f;
        for (int r = 0; r < 32; ++r) {
            float p = SR[(size_t)(row0 + r) * H + k] * wv;
            #pragma unroll
            for (int off = 32; off; off >>= 1) p += __shfl_down(p, off);
            if (l == 0) atomicAdd(mention + row0 + r, p + bm_add);
        }
        return;
    }

    const short* __restrict__ Wt = z ? WtB : WtA;
    float* __restrict__ out = z ? BJ : AI;

    const int m0 = blockIdx.x * 32, n0 = blockIdx.y * 32;
    const int lr = l & 15, lg = l >> 4;

    const float* arow[2];
    #pragma unroll
    for (int i = 0; i < 2; ++i)
        arow[i] = SR + (size_t)(m0 + 16*i + lr) * H + lg * 8;
    const short* brow[2];
    #pragma unroll
    for (int j = 0; j < 2; ++j)
        brow[j] = Wt + (size_t)(n0 + 16*j + lr) * H + lg * 8;

    f32x4 acc[2][2] = {};
    #pragma unroll 2
    for (int k0 = 0; k0 < H; k0 += 32) {
        s16x8 a[2], bf[2];
        #pragma unroll
        for (int i = 0; i < 2; ++i) {
            float4 v0 = *(const float4*)(arow[i] + k0);
            float4 v1 = *(const float4*)(arow[i] + k0 + 4);
            a[i] = cvt8(v0, v1);
        }
        #pragma unroll
        for (int j = 0; j < 2; ++j)
            bf[j] = *(const s16x8*)(brow[j] + k0);
        #pragma unroll
        for (int i = 0; i < 2; ++i)
            #pragma unroll
            for (int j = 0; j < 2; ++j)
                acc[i][j] = __builtin_amdgcn_mfma_f32_16x16x32_bf16(a[i], bf[j], acc[i][j], 0, 0, 0);
    }

    #pragma unroll
    for (int j = 0; j < 2; ++j) {
        const int col = n0 + 16*j + lr;
        const float bv = z ? 0.f : b1[col];
        #pragma unroll
        for (int i = 0; i < 2; ++i) {
            const int rbase = m0 + 16*i + lg*4;
            #pragma unroll
            for (int r = 0; r < 4; ++r)
                out[(size_t)(rbase + r) * H + col] = acc[i][j][r] + bv;
        }
    }
}

// ---------------------------------------------------------------------------
// G4: pair[b,i,j] = (j<i) ? sum_h relu(AI[b,i,h]+BJ[b,j,h])*W2[h] + b2 : 0
// Grid: 36 lower-triangle 16x16 tiles per batch (upper region pre-zeroed).
// ---------------------------------------------------------------------------
__global__ __launch_bounds__(256) void k_pair(
    const float* __restrict__ AI, const float* __restrict__ BJ,
    const float* __restrict__ W2, const float* __restrict__ b2,
    float* __restrict__ pair)
{
    const int tid = threadIdx.x;
    const int t = blockIdx.x;
    int by = (int)((sqrtf(8.f * t + 1.f) - 1.f) * 0.5f);
    while ((by + 1) * (by + 2) / 2 <= t) ++by;
    while (by * (by + 1) / 2 > t) --by;
    const int bx = t - by * (by + 1) / 2;
    const int bz = blockIdx.y;

    const int tx = tid & 15, ty = tid >> 4;
    const int i = by * 16 + ty, j = bx * 16 + tx;

    __shared__ __align__(16) float Ais[16][68];
    __shared__ __align__(16) float Bjs[16][68];
    __shared__ __align__(16) float w2s[768];
    for (int q = tid; q < 768; q += 256) w2s[q] = W2[q];

    const int sr = tid >> 4, sc = (tid & 15) << 2;
    float acc = 0.f;

    for (int ch = 0; ch < 12; ++ch) {
        __syncthreads();
        *(float4*)&Ais[sr][sc] =
            *(const float4*)(AI + ((size_t)bz * NSPAN + by*16 + sr) * H + ch*64 + sc);
        *(float4*)&Bjs[sr][sc] =
            *(const float4*)(BJ + ((size_t)bz * NSPAN + bx*16 + sr) * H + ch*64 + sc);
        __syncthreads();
        #pragma unroll
        for (int hq = 0; hq < 16; ++hq) {
            float4 a = *(const float4*)&Ais[ty][hq << 2];
            float4 b = *(const float4*)&Bjs[tx][hq << 2];
            float4 w = *(const float4*)&w2s[ch*64 + (hq << 2)];
            acc = fmaf(fmaxf(a.x + b.x, 0.f), w.x, acc);
            acc = fmaf(fmaxf(a.y + b.y, 0.f), w.y, acc);
            acc = fmaf(fmaxf(a.z + b.z, 0.f), w.z, acc);
            acc = fmaf(fmaxf(a.w + b.w, 0.f), w.w, acc);
        }
    }
    if (j < i)
        pair[((size_t)bz * NSPAN + i) * NSPAN + j] = acc + b2[0];
}

// ---------------------------------------------------------------------------
extern "C" void kernel_launch(void* const* d_in, const int* in_sizes, int n_in,
                              void* d_out, int out_size, void* d_ws, size_t ws_size,
                              hipStream_t stream)
{
    const float* seq    = (const float*)d_in[0];
    const int*   starts = (const int*)  d_in[1];
    const int*   ends   = (const int*)  d_in[2];
    const float* Ws     = (const float*)d_in[3];
    const float* bs     = (const float*)d_in[4];
    const float* We     = (const float*)d_in[5];
    const float* be     = (const float*)d_in[6];
    const float* wemb   = (const float*)d_in[7];
    const float* Wout   = (const float*)d_in[8];
    const float* bout   = (const float*)d_in[9];
    const float* Wm     = (const float*)d_in[10];
    const float* bment  = (const float*)d_in[11];
    const float* W1     = (const float*)d_in[12];
    const float* b1     = (const float*)d_in[13];
    const float* W2     = (const float*)d_in[14];
    const float* b2     = (const float*)d_in[15];

    float* ws   = (float*)d_ws;
    float* Xcat = ws;                    // 512*1568  = 802816 f
    float* SR   = ws + 802816;           // 512*768   = 393216 f
    float* AI   = ws + 1196032;          // 393216 f
    float* BJ   = ws + 1589248;          // 393216 f
    short* Wt_s   = (short*)(ws + 1982464);      // 768*768 bf16
    short* Wt_e   = Wt_s + 589824;
    short* WtA    = Wt_e + 589824;
    short* WtB    = WtA + 589824;
    short* Wt_out = WtB + 589824;                // 768*1568 bf16

    float* out_mention = (float*)d_out;          // 512
    float* out_pair    = (float*)d_out + 512;    // 4*128*128

    hipMemsetAsync(d_out, 0, (size_t)out_size * sizeof(float), stream);

    hipLaunchKernelGGL(k_prep, dim3(3544), dim3(256), 0, stream,
                       Ws, We, W1, Wout, wemb, starts, ends,
                       Wt_s, Wt_e, WtA, WtB, Wt_out, Xcat);
    hipLaunchKernelGGL(k_g1, dim3(16, 24, 2), dim3(64), 0, stream,
                       seq, starts, ends, Wt_s, Wt_e, bs, be, Xcat);
    hipLaunchKernelGGL(k_g2, dim3(16, 24), dim3(64), 0, stream,
                       Xcat, Wt_out, bout, SR);
    hipLaunchKernelGGL(k_g3, dim3(16, 24, 3), dim3(64), 0, stream,
                       SR, WtA, WtB, b1, Wm, bment, AI, BJ, out_mention);
    hipLaunchKernelGGL(k_pair, dim3(36, 4), dim3(256), 0, stream,
                       AI, BJ, W2, b2, out_pair);
}

// Round 3
// 67.533 us; speedup vs baseline: 2.7285x; 2.0208x over previous
//
#include <hip/hip_runtime.h>
#include <hip/hip_bf16.h>

#define H 768
#define K2P 1600          // 768 + 768 + 64 (width 30 padded to 64)
#define SEQLEN 512
#define NSPAN 128

typedef __attribute__((ext_vector_type(8))) short s16x8;
typedef __attribute__((ext_vector_type(4))) float f32x4;

__device__ __forceinline__ short f2bf(float f) {
    __hip_bfloat16 h = __float2bfloat16(f);
    return *reinterpret_cast<short*>(&h);
}
__device__ __forceinline__ float bf2f(short s) {
    unsigned int u = ((unsigned int)(unsigned short)s) << 16;
    return __builtin_bit_cast(float, u);
}

__device__ __forceinline__ void gload16(const void* g, void* l) {
    __builtin_amdgcn_global_load_lds(
        (const __attribute__((address_space(1))) unsigned int*)g,
        (__attribute__((address_space(3))) unsigned int*)l, 16, 0, 0);
}

#define FENCE() asm volatile("" ::: "memory")
#define WAITALL() asm volatile("s_waitcnt vmcnt(0) lgkmcnt(0)" ::: "memory")
#define BAR() do { FENCE(); __builtin_amdgcn_s_barrier(); FENCE(); } while (0)

// Stage one 64-k tile: A[32 rows][64k] + W[64 rows][64k] bf16 into LDS.
// LDS layout: A at shorts[0..2047], B at shorts[2048..6143]; row = 128B.
// Pre-swizzled global source (slot ^ row&7) -> linear LDS dest (rule #21).
__device__ __forceinline__ void stage64(
    const short* __restrict__ A, int ldA, int am0,
    const short* __restrict__ W, int ldW, int n0,
    int k0, short* lbuf, int w, int l)
{
    const int rl = l >> 3, s = l & 7;
    #pragma unroll
    for (int q = 0; q < 2; ++q) {
        const int row = w*16 + q*8 + rl;
        const short* src = A + (size_t)(am0 + row) * ldA + k0 + ((s ^ (row & 7)) << 3);
        gload16(src, lbuf + (w*16 + q*8) * 64);
    }
    #pragma unroll
    for (int q = 0; q < 4; ++q) {
        const int row = w*32 + q*8 + rl;
        const short* src = W + (size_t)(n0 + row) * ldW + k0 + ((s ^ (row & 7)) << 3);
        gload16(src, lbuf + 2048 + (w*32 + q*8) * 64);
    }
}

// One BK=64 step: 8 ds_read_b128 (swizzled) + 8 MFMA. Wave w owns cols w*32..+31.
__device__ __forceinline__ void mfma_step(const short* lbuf, int w, int l, f32x4 acc[2][2])
{
    const int r = l & 15, hi = l >> 4;
    #pragma unroll
    for (int kc = 0; kc < 2; ++kc) {
        s16x8 av[2], bv[2];
        #pragma unroll
        for (int i = 0; i < 2; ++i) {
            const int row = i*16 + r;
            const int byt = row*128 + ((kc*64 + hi*16) ^ ((row & 7) << 4));
            av[i] = *(const s16x8*)((const char*)lbuf + byt);
        }
        #pragma unroll
        for (int j = 0; j < 2; ++j) {
            const int row = w*32 + j*16 + r;
            const int byt = 4096 + row*128 + ((kc*64 + hi*16) ^ ((row & 7) << 4));
            bv[j] = *(const s16x8*)((const char*)lbuf + byt);
        }
        #pragma unroll
        for (int i = 0; i < 2; ++i)
            #pragma unroll
            for (int j = 0; j < 2; ++j)
                acc[i][j] = __builtin_amdgcn_mfma_f32_16x16x32_bf16(av[i], bv[j], acc[i][j], 0, 0, 0);
    }
}

#define GEMM_PIPE(APTR, LDA, AM0, WPTR, LDW, N0, NSTEPS)                       \
    f32x4 acc[2][2] = {};                                                      \
    stage64(APTR, LDA, AM0, WPTR, LDW, N0, 0, lds[0], w, l);                   \
    WAITALL(); BAR();                                                          \
    for (int s = 0; s < (NSTEPS); ++s) {                                       \
        if (s + 1 < (NSTEPS))                                                  \
            stage64(APTR, LDA, AM0, WPTR, LDW, N0, (s+1)*64, lds[(s+1)&1], w, l); \
        mfma_step(lds[s & 1], w, l, acc);                                      \
        WAITALL(); BAR();                                                      \
    }

// ---------------------------------------------------------------------------
// P0: weight transposes -> bf16 [n][k]; gather seq -> Xg bf16; Xcat width cols.
// ---------------------------------------------------------------------------
__global__ __launch_bounds__(256) void k_prep(
    const float* __restrict__ seq,
    const int* __restrict__ starts, const int* __restrict__ ends,
    const float* __restrict__ Ws, const float* __restrict__ We,
    const float* __restrict__ W1, const float* __restrict__ Wout,
    const float* __restrict__ wemb,
    short* __restrict__ WtSE, short* __restrict__ WtAB,
    short* __restrict__ WtOut, short* __restrict__ Xg, short* __restrict__ Xcat)
{
    const int b = blockIdx.x;
    const int tid = threadIdx.x;

    if (b < 2304) {                       // Ws/We/Wa+Wc/Wb-Wc transposes
        const int sec = b / 576;
        const int t = b % 576;
        const int kt = t / 24, nt = t % 24;
        __shared__ float tile[32][33];
        const int kk = tid >> 3;
        const int c4 = (tid & 7) << 2;
        const int srow = kt * 32 + kk, scol = nt * 32 + c4;
        float4 v;
        if (sec == 0)      v = *(const float4*)(Ws + (size_t)srow * H + scol);
        else if (sec == 1) v = *(const float4*)(We + (size_t)srow * H + scol);
        else {
            const float* base = W1 + (size_t)(sec == 2 ? 0 : H) * H;
            float4 u = *(const float4*)(base + (size_t)srow * H + scol);
            float4 c = *(const float4*)(W1 + (size_t)2*H*H + (size_t)srow * H + scol);
            const float sg = (sec == 2) ? 1.f : -1.f;
            v = make_float4(fmaf(sg,c.x,u.x), fmaf(sg,c.y,u.y),
                            fmaf(sg,c.z,u.z), fmaf(sg,c.w,u.w));
        }
        tile[kk][c4+0]=v.x; tile[kk][c4+1]=v.y; tile[kk][c4+2]=v.z; tile[kk][c4+3]=v.w;
        __syncthreads();
        short* dst = (sec < 2 ? WtSE : WtAB) + (size_t)(sec & 1) * H * H;
        const int nn = tid >> 3;
        short4 o;
        o.x = f2bf(tile[c4+0][nn]); o.y = f2bf(tile[c4+1][nn]);
        o.z = f2bf(tile[c4+2][nn]); o.w = f2bf(tile[c4+3][nn]);
        *(short4*)(dst + (size_t)(nt*32 + nn) * H + kt*32 + c4) = o;
    } else if (b < 3504) {                // Wout^T -> [768][1600], zero-padded
        const int t = b - 2304;
        const int nt = t / 50, kt = t % 50;
        __shared__ float tile[32][33];
        const int kk = tid >> 3;
        const int c4 = (tid & 7) << 2;
        const int srow = kt * 32 + kk, scol = nt * 32 + c4;
        float4 v = make_float4(0.f, 0.f, 0.f, 0.f);
        if (srow < 1566) v = *(const float4*)(Wout + (size_t)srow * H + scol);
        tile[kk][c4+0]=v.x; tile[kk][c4+1]=v.y; tile[kk][c4+2]=v.z; tile[kk][c4+3]=v.w;
        __syncthreads();
        const int nn = tid >> 3;
        short4 o;
        o.x = f2bf(tile[c4+0][nn]); o.y = f2bf(tile[c4+1][nn]);
        o.z = f2bf(tile[c4+2][nn]); o.w = f2bf(tile[c4+3][nn]);
        *(short4*)(WtOut + (size_t)(nt*32 + nn) * K2P + kt*32 + c4) = o;
    } else if (b < 3760) {                // gather: Xg[0:512)=starts, [512:1024)=ends
        const int gr = (b - 3504) * 4 + (tid >> 6);
        const int c = tid & 63;
        const int spanrow = gr & 511;
        const int idx = (gr < 512) ? starts[spanrow] : ends[spanrow];
        const size_t base = ((size_t)(spanrow >> 7) * SEQLEN + idx) * H;
        #pragma unroll
        for (int i = 0; i < 12; ++i) {
            const int col = c + i*64;
            Xg[(size_t)gr * H + col] = f2bf(seq[base + col]);
        }
    } else {                              // Xcat width-emb cols 1536..1599
        const int t = (b - 3760) * 256 + tid;
        const int row = t >> 6, c = t & 63;
        int wd = ends[row] - starts[row];
        wd = wd < 0 ? 0 : (wd > 10 ? 10 : wd);
        Xcat[(size_t)row * K2P + 1536 + c] = (c < 30) ? f2bf(wemb[wd*30 + c]) : (short)0;
    }
}

// ---------------------------------------------------------------------------
// G1: Xcat[:, gc] = Xg(half) @ WtSE^T + bias   (N = 1536, both halves)
// ---------------------------------------------------------------------------
__global__ __launch_bounds__(128) void k_g1(
    const short* __restrict__ Xg, const short* __restrict__ WtSE,
    const float* __restrict__ bs, const float* __restrict__ be,
    short* __restrict__ Xcat)
{
    __shared__ __align__(16) short lds[2][6144];
    const int l = threadIdx.x & 63, w = threadIdx.x >> 6;
    const int bm = blockIdx.x, n0 = blockIdx.y * 64;
    const int am0 = (n0 >= 768 ? 512 : 0) + bm * 32;

    GEMM_PIPE(Xg, H, am0, WtSE, H, n0, 12)

    const int r = l & 15, hi = l >> 4;
    #pragma unroll
    for (int j = 0; j < 2; ++j) {
        const int gc = n0 + w*32 + j*16 + r;
        const float bv = (gc < 768) ? bs[gc] : be[gc - 768];
        #pragma unroll
        for (int i = 0; i < 2; ++i) {
            const int rbase = bm*32 + i*16 + hi*4;
            #pragma unroll
            for (int rg = 0; rg < 4; ++rg)
                Xcat[(size_t)(rbase + rg) * K2P + gc] = f2bf(acc[i][j][rg] + bv);
        }
    }
}

// ---------------------------------------------------------------------------
// G2: SR = Xcat(K=1600) @ WtOut^T + b_out
// ---------------------------------------------------------------------------
__global__ __launch_bounds__(128) void k_g2(
    const short* __restrict__ Xcat, const short* __restrict__ WtOut,
    const float* __restrict__ bout, short* __restrict__ SR)
{
    __shared__ __align__(16) short lds[2][6144];
    const int l = threadIdx.x & 63, w = threadIdx.x >> 6;
    const int bm = blockIdx.x, n0 = blockIdx.y * 64;

    GEMM_PIPE(Xcat, K2P, bm*32, WtOut, K2P, n0, 25)

    const int r = l & 15, hi = l >> 4;
    #pragma unroll
    for (int j = 0; j < 2; ++j) {
        const int gc = n0 + w*32 + j*16 + r;
        const float bv = bout[gc];
        #pragma unroll
        for (int i = 0; i < 2; ++i) {
            const int rbase = bm*32 + i*16 + hi*4;
            #pragma unroll
            for (int rg = 0; rg < 4; ++rg)
                SR[(size_t)(rbase + rg) * H + gc] = f2bf(acc[i][j][rg] + bv);
        }
    }
}

// ---------------------------------------------------------------------------
// G3: bn<24: AB[:, gc] = SR @ WtAB^T (+b1 first half)   [fp32 out]
//     bn==24: mention = SR @ Wm + b_ment
// ---------------------------------------------------------------------------
__global__ __launch_bounds__(128) void k_g3(
    const short* __restrict__ SR, const short* __restrict__ WtAB,
    const float* __restrict__ b1, const float* __restrict__ Wm,
    const float* __restrict__ bment,
    float* __restrict__ AB, float* __restrict__ mention)
{
    const int l = threadIdx.x & 63, w = threadIdx.x >> 6;
    const int bm = blockIdx.x;

    if (blockIdx.y == 24) {               // mention scores, 32 rows per block
        const int rows0 = bm*32 + w*16;
        for (int rr = 0; rr < 16; ++rr) {
            const int row = rows0 + rr;
            float p = 0.f;
            #pragma unroll
            for (int kk = 0; kk < 12; ++kk) {
                const int k = kk*64 + l;
                p = fmaf(bf2f(SR[(size_t)row * H + k]), Wm[k], p);
            }
            #pragma unroll
            for (int off = 32; off; off >>= 1) p += __shfl_down(p, off);
            if (l == 0) mention[row] = p + bment[0];
        }
        return;
    }

    __shared__ __align__(16) short lds[2][6144];
    const int n0 = blockIdx.y * 64;

    GEMM_PIPE(SR, H, bm*32, WtAB, H, n0, 12)

    const int r = l & 15, hi = l >> 4;
    #pragma unroll
    for (int j = 0; j < 2; ++j) {
        const int gc = n0 + w*32 + j*16 + r;
        const float bv = (gc < 768) ? b1[gc] : 0.f;
        #pragma unroll
        for (int i = 0; i < 2; ++i) {
            const int rbase = bm*32 + i*16 + hi*4;
            #pragma unroll
            for (int rg = 0; rg < 4; ++rg)
                AB[(size_t)(rbase + rg) * 1536 + gc] = acc[i][j][rg] + bv;
        }
    }
}

// ---------------------------------------------------------------------------
// G4: pair[b,i,j] = (j<i) ? sum_h relu(AI+BJ)*W2[h] + b2 : 0
// AB = [512][1536] fp32, AI at +0 (b1 folded), BJ at +768.
// ---------------------------------------------------------------------------
__global__ __launch_bounds__(256) void k_pair(
    const float* __restrict__ AB, const float* __restrict__ W2,
    const float* __restrict__ b2, float* __restrict__ pair)
{
    const int tid = threadIdx.x;
    const int t = blockIdx.x;
    int by = (int)((sqrtf(8.f * t + 1.f) - 1.f) * 0.5f);
    while ((by + 1) * (by + 2) / 2 <= t) ++by;
    while (by * (by + 1) / 2 > t) --by;
    const int bx = t - by * (by + 1) / 2;
    const int bz = blockIdx.y;

    const int tx = tid & 15, ty = tid >> 4;
    const int i = by * 16 + ty, j = bx * 16 + tx;

    __shared__ __align__(16) float Ais[16][68];
    __shared__ __align__(16) float Bjs[16][68];
    __shared__ __align__(16) float w2s[768];
    for (int q = tid; q < 768; q += 256) w2s[q] = W2[q];

    const int sr = tid >> 4, sc = (tid & 15) << 2;
    float acc = 0.f;

    for (int ch = 0; ch < 12; ++ch) {
        __syncthreads();
        *(float4*)&Ais[sr][sc] =
            *(const float4*)(AB + ((size_t)bz*NSPAN + by*16 + sr)*1536 + ch*64 + sc);
        *(float4*)&Bjs[sr][sc] =
            *(const float4*)(AB + ((size_t)bz*NSPAN + bx*16 + sr)*1536 + 768 + ch*64 + sc);
        __syncthreads();
        #pragma unroll
        for (int hq = 0; hq < 16; ++hq) {
            float4 a = *(const float4*)&Ais[ty][hq << 2];
            float4 b = *(const float4*)&Bjs[tx][hq << 2];
            float4 wv = *(const float4*)&w2s[ch*64 + (hq << 2)];
            acc = fmaf(fmaxf(a.x + b.x, 0.f), wv.x, acc);
            acc = fmaf(fmaxf(a.y + b.y, 0.f), wv.y, acc);
            acc = fmaf(fmaxf(a.z + b.z, 0.f), wv.z, acc);
            acc = fmaf(fmaxf(a.w + b.w, 0.f), wv.w, acc);
        }
    }
    if (j < i)
        pair[((size_t)bz*NSPAN + i)*NSPAN + j] = acc + b2[0];
}

// ---------------------------------------------------------------------------
extern "C" void kernel_launch(void* const* d_in, const int* in_sizes, int n_in,
                              void* d_out, int out_size, void* d_ws, size_t ws_size,
                              hipStream_t stream)
{
    const float* seq    = (const float*)d_in[0];
    const int*   starts = (const int*)  d_in[1];
    const int*   ends   = (const int*)  d_in[2];
    const float* Ws     = (const float*)d_in[3];
    const float* bs     = (const float*)d_in[4];
    const float* We     = (const float*)d_in[5];
    const float* be     = (const float*)d_in[6];
    const float* wemb   = (const float*)d_in[7];
    const float* Wout   = (const float*)d_in[8];
    const float* bout   = (const float*)d_in[9];
    const float* Wm     = (const float*)d_in[10];
    const float* bment  = (const float*)d_in[11];
    const float* W1     = (const float*)d_in[12];
    const float* b1     = (const float*)d_in[13];
    const float* W2     = (const float*)d_in[14];
    const float* b2     = (const float*)d_in[15];

    float* ws = (float*)d_ws;
    float* AB    = ws;                          // 512*1536 fp32
    short* Xg    = (short*)(ws + 786432);       // 1024*768 bf16
    short* Xcat  = (short*)(ws + 1179648);      // 512*1600 bf16
    short* SR    = (short*)(ws + 1589248);      // 512*768  bf16
    short* WtSE  = (short*)(ws + 1785856);      // 1536*768 bf16
    short* WtAB  = (short*)(ws + 2375680);      // 1536*768 bf16
    short* WtOut = (short*)(ws + 2965504);      // 768*1600 bf16

    float* out_mention = (float*)d_out;         // 512
    float* out_pair    = (float*)d_out + 512;   // 4*128*128

    hipMemsetAsync(d_out, 0, (size_t)out_size * sizeof(float), stream);

    hipLaunchKernelGGL(k_prep, dim3(3888), dim3(256), 0, stream,
                       seq, starts, ends, Ws, We, W1, Wout, wemb,
                       WtSE, WtAB, WtOut, Xg, Xcat);
    hipLaunchKernelGGL(k_g1, dim3(16, 24), dim3(128), 0, stream,
                       Xg, WtSE, bs, be, Xcat);
    hipLaunchKernelGGL(k_g2, dim3(16, 12), dim3(128), 0, stream,
                       Xcat, WtOut, bout, SR);
    hipLaunchKernelGGL(k_g3, dim3(16, 25), dim3(128), 0, stream,
                       SR, WtAB, b1, Wm, bment, AB, out_mention);
    hipLaunchKernelGGL(k_pair, dim3(36, 4), dim3(256), 0, stream,
                       AB, W2, b2, out_pair);
}

// Round 4
// 62.493 us; speedup vs baseline: 2.9485x; 1.0806x over previous
//
#include <hip/hip_runtime.h>
#include <hip/hip_bf16.h>

#define H 768
#define K2P 1600          // 768 + 768 + 64 (width 30 padded to 64)
#define SEQLEN 512
#define NSPAN 128

typedef __attribute__((ext_vector_type(8))) short s16x8;
typedef __attribute__((ext_vector_type(4))) float f32x4;

__device__ __forceinline__ short f2bf(float f) {
    __hip_bfloat16 h = __float2bfloat16(f);
    return *reinterpret_cast<short*>(&h);
}
__device__ __forceinline__ float bf2f(short s) {
    unsigned int u = ((unsigned int)(unsigned short)s) << 16;
    return __builtin_bit_cast(float, u);
}

__device__ __forceinline__ void gload16(const void* g, void* l) {
    __builtin_amdgcn_global_load_lds(
        (const __attribute__((address_space(1))) unsigned int*)g,
        (__attribute__((address_space(3))) unsigned int*)l, 16, 0, 0);
}

#define FENCE() asm volatile("" ::: "memory")
#define WAITALL() asm volatile("s_waitcnt vmcnt(0) lgkmcnt(0)" ::: "memory")
#define BAR() do { FENCE(); __builtin_amdgcn_s_barrier(); FENCE(); } while (0)

// Stage one 64-k tile: A[32 rows][64k] + W[64 rows][64k] bf16 into LDS.
// LDS layout: A at shorts[0..2047], B at shorts[2048..6143]; row = 128B.
// Pre-swizzled global source (slot ^ row&7) -> linear LDS dest (rule #21).
__device__ __forceinline__ void stage64(
    const short* __restrict__ A, int ldA, int am0,
    const short* __restrict__ W, int ldW, int n0,
    int k0, short* lbuf, int w, int l)
{
    const int rl = l >> 3, s = l & 7;
    #pragma unroll
    for (int q = 0; q < 2; ++q) {
        const int row = w*16 + q*8 + rl;
        const short* src = A + (size_t)(am0 + row) * ldA + k0 + ((s ^ (row & 7)) << 3);
        gload16(src, lbuf + (w*16 + q*8) * 64);
    }
    #pragma unroll
    for (int q = 0; q < 4; ++q) {
        const int row = w*32 + q*8 + rl;
        const short* src = W + (size_t)(n0 + row) * ldW + k0 + ((s ^ (row & 7)) << 3);
        gload16(src, lbuf + 2048 + (w*32 + q*8) * 64);
    }
}

// One BK=64 step: 8 ds_read_b128 (swizzled) + 8 MFMA. Wave w owns cols w*32..+31.
__device__ __forceinline__ void mfma_step(const short* lbuf, int w, int l, f32x4 acc[2][2])
{
    const int r = l & 15, hi = l >> 4;
    #pragma unroll
    for (int kc = 0; kc < 2; ++kc) {
        s16x8 av[2], bv[2];
        #pragma unroll
        for (int i = 0; i < 2; ++i) {
            const int row = i*16 + r;
            const int byt = row*128 + ((kc*64 + hi*16) ^ ((row & 7) << 4));
            av[i] = *(const s16x8*)((const char*)lbuf + byt);
        }
        #pragma unroll
        for (int j = 0; j < 2; ++j) {
            const int row = w*32 + j*16 + r;
            const int byt = 4096 + row*128 + ((kc*64 + hi*16) ^ ((row & 7) << 4));
            bv[j] = *(const s16x8*)((const char*)lbuf + byt);
        }
        #pragma unroll
        for (int i = 0; i < 2; ++i)
            #pragma unroll
            for (int j = 0; j < 2; ++j)
                acc[i][j] = __builtin_amdgcn_mfma_f32_16x16x32_bf16(av[i], bv[j], acc[i][j], 0, 0, 0);
    }
}

#define GEMM_PIPE(APTR, LDA, AM0, WPTR, LDW, N0, NSTEPS)                       \
    f32x4 acc[2][2] = {};                                                      \
    stage64(APTR, LDA, AM0, WPTR, LDW, N0, 0, lds[0], w, l);                   \
    WAITALL(); BAR();                                                          \
    for (int s = 0; s < (NSTEPS); ++s) {                                       \
        if (s + 1 < (NSTEPS))                                                  \
            stage64(APTR, LDA, AM0, WPTR, LDW, N0, (s+1)*64, lds[(s+1)&1], w, l); \
        mfma_step(lds[s & 1], w, l, acc);                                      \
        WAITALL(); BAR();                                                      \
    }

// ---------------------------------------------------------------------------
// P0: weight transposes -> bf16 [n][k]; gather seq -> Xg bf16; Xcat width cols.
// ---------------------------------------------------------------------------
__global__ __launch_bounds__(256) void k_prep(
    const float* __restrict__ seq,
    const int* __restrict__ starts, const int* __restrict__ ends,
    const float* __restrict__ Ws, const float* __restrict__ We,
    const float* __restrict__ W1, const float* __restrict__ Wout,
    const float* __restrict__ wemb,
    short* __restrict__ WtSE, short* __restrict__ WtAB,
    short* __restrict__ WtOut, short* __restrict__ Xg, short* __restrict__ Xcat)
{
    const int b = blockIdx.x;
    const int tid = threadIdx.x;

    if (b < 2304) {                       // Ws/We/Wa+Wc/Wb-Wc transposes
        const int sec = b / 576;
        const int t = b % 576;
        const int kt = t / 24, nt = t % 24;
        __shared__ float tile[32][33];
        const int kk = tid >> 3;
        const int c4 = (tid & 7) << 2;
        const int srow = kt * 32 + kk, scol = nt * 32 + c4;
        float4 v;
        if (sec == 0)      v = *(const float4*)(Ws + (size_t)srow * H + scol);
        else if (sec == 1) v = *(const float4*)(We + (size_t)srow * H + scol);
        else {
            const float* base = W1 + (size_t)(sec == 2 ? 0 : H) * H;
            float4 u = *(const float4*)(base + (size_t)srow * H + scol);
            float4 c = *(const float4*)(W1 + (size_t)2*H*H + (size_t)srow * H + scol);
            const float sg = (sec == 2) ? 1.f : -1.f;
            v = make_float4(fmaf(sg,c.x,u.x), fmaf(sg,c.y,u.y),
                            fmaf(sg,c.z,u.z), fmaf(sg,c.w,u.w));
        }
        tile[kk][c4+0]=v.x; tile[kk][c4+1]=v.y; tile[kk][c4+2]=v.z; tile[kk][c4+3]=v.w;
        __syncthreads();
        short* dst = (sec < 2 ? WtSE : WtAB) + (size_t)(sec & 1) * H * H;
        const int nn = tid >> 3;
        short4 o;
        o.x = f2bf(tile[c4+0][nn]); o.y = f2bf(tile[c4+1][nn]);
        o.z = f2bf(tile[c4+2][nn]); o.w = f2bf(tile[c4+3][nn]);
        *(short4*)(dst + (size_t)(nt*32 + nn) * H + kt*32 + c4) = o;
    } else if (b < 3504) {                // Wout^T -> [768][1600], zero-padded
        const int t = b - 2304;
        const int nt = t / 50, kt = t % 50;
        __shared__ float tile[32][33];
        const int kk = tid >> 3;
        const int c4 = (tid & 7) << 2;
        const int srow = kt * 32 + kk, scol = nt * 32 + c4;
        float4 v = make_float4(0.f, 0.f, 0.f, 0.f);
        if (srow < 1566) v = *(const float4*)(Wout + (size_t)srow * H + scol);
        tile[kk][c4+0]=v.x; tile[kk][c4+1]=v.y; tile[kk][c4+2]=v.z; tile[kk][c4+3]=v.w;
        __syncthreads();
        const int nn = tid >> 3;
        short4 o;
        o.x = f2bf(tile[c4+0][nn]); o.y = f2bf(tile[c4+1][nn]);
        o.z = f2bf(tile[c4+2][nn]); o.w = f2bf(tile[c4+3][nn]);
        *(short4*)(WtOut + (size_t)(nt*32 + nn) * K2P + kt*32 + c4) = o;
    } else if (b < 3760) {                // gather: Xg[0:512)=starts, [512:1024)=ends
        const int gr = (b - 3504) * 4 + (tid >> 6);
        const int c = tid & 63;
        const int spanrow = gr & 511;
        const int idx = (gr < 512) ? starts[spanrow] : ends[spanrow];
        const size_t base = ((size_t)(spanrow >> 7) * SEQLEN + idx) * H;
        #pragma unroll
        for (int i = 0; i < 12; ++i) {
            const int col = c + i*64;
            Xg[(size_t)gr * H + col] = f2bf(seq[base + col]);
        }
    } else {                              // Xcat width-emb cols 1536..1599
        const int t = (b - 3760) * 256 + tid;
        const int row = t >> 6, c = t & 63;
        int wd = ends[row] - starts[row];
        wd = wd < 0 ? 0 : (wd > 10 ? 10 : wd);
        Xcat[(size_t)row * K2P + 1536 + c] = (c < 30) ? f2bf(wemb[wd*30 + c]) : (short)0;
    }
}

// ---------------------------------------------------------------------------
// G1: Xcat[:, gc] = Xg(half) @ WtSE^T + bias   (N = 1536, both halves)
// ---------------------------------------------------------------------------
__global__ __launch_bounds__(128) void k_g1(
    const short* __restrict__ Xg, const short* __restrict__ WtSE,
    const float* __restrict__ bs, const float* __restrict__ be,
    short* __restrict__ Xcat)
{
    __shared__ __align__(16) short lds[2][6144];
    const int l = threadIdx.x & 63, w = threadIdx.x >> 6;
    const int bm = blockIdx.x, n0 = blockIdx.y * 64;
    const int am0 = (n0 >= 768 ? 512 : 0) + bm * 32;

    GEMM_PIPE(Xg, H, am0, WtSE, H, n0, 12)

    const int r = l & 15, hi = l >> 4;
    #pragma unroll
    for (int j = 0; j < 2; ++j) {
        const int gc = n0 + w*32 + j*16 + r;
        const float bv = (gc < 768) ? bs[gc] : be[gc - 768];
        #pragma unroll
        for (int i = 0; i < 2; ++i) {
            const int rbase = bm*32 + i*16 + hi*4;
            #pragma unroll
            for (int rg = 0; rg < 4; ++rg)
                Xcat[(size_t)(rbase + rg) * K2P + gc] = f2bf(acc[i][j][rg] + bv);
        }
    }
}

// ---------------------------------------------------------------------------
// G2: SR = Xcat(K=1600) @ WtOut^T + b_out
// ---------------------------------------------------------------------------
__global__ __launch_bounds__(128) void k_g2(
    const short* __restrict__ Xcat, const short* __restrict__ WtOut,
    const float* __restrict__ bout, short* __restrict__ SR)
{
    __shared__ __align__(16) short lds[2][6144];
    const int l = threadIdx.x & 63, w = threadIdx.x >> 6;
    const int bm = blockIdx.x, n0 = blockIdx.y * 64;

    GEMM_PIPE(Xcat, K2P, bm*32, WtOut, K2P, n0, 25)

    const int r = l & 15, hi = l >> 4;
    #pragma unroll
    for (int j = 0; j < 2; ++j) {
        const int gc = n0 + w*32 + j*16 + r;
        const float bv = bout[gc];
        #pragma unroll
        for (int i = 0; i < 2; ++i) {
            const int rbase = bm*32 + i*16 + hi*4;
            #pragma unroll
            for (int rg = 0; rg < 4; ++rg)
                SR[(size_t)(rbase + rg) * H + gc] = f2bf(acc[i][j][rg] + bv);
        }
    }
}

// ---------------------------------------------------------------------------
// G3: bn<24: AB[:, gc] = SR @ WtAB^T (+b1 first half)   [fp32 out]
//     bn==24: mention = SR @ Wm + b_ment
// ---------------------------------------------------------------------------
__global__ __launch_bounds__(128) void k_g3(
    const short* __restrict__ SR, const short* __restrict__ WtAB,
    const float* __restrict__ b1, const float* __restrict__ Wm,
    const float* __restrict__ bment,
    float* __restrict__ AB, float* __restrict__ mention)
{
    const int l = threadIdx.x & 63, w = threadIdx.x >> 6;
    const int bm = blockIdx.x;

    if (blockIdx.y == 24) {               // mention scores, 32 rows per block
        const int rows0 = bm*32 + w*16;
        for (int rr = 0; rr < 16; ++rr) {
            const int row = rows0 + rr;
            float p = 0.f;
            #pragma unroll
            for (int kk = 0; kk < 12; ++kk) {
                const int k = kk*64 + l;
                p = fmaf(bf2f(SR[(size_t)row * H + k]), Wm[k], p);
            }
            #pragma unroll
            for (int off = 32; off; off >>= 1) p += __shfl_down(p, off);
            if (l == 0) mention[row] = p + bment[0];
        }
        return;
    }

    __shared__ __align__(16) short lds[2][6144];
    const int n0 = blockIdx.y * 64;

    GEMM_PIPE(SR, H, bm*32, WtAB, H, n0, 12)

    const int r = l & 15, hi = l >> 4;
    #pragma unroll
    for (int j = 0; j < 2; ++j) {
        const int gc = n0 + w*32 + j*16 + r;
        const float bv = (gc < 768) ? b1[gc] : 0.f;
        #pragma unroll
        for (int i = 0; i < 2; ++i) {
            const int rbase = bm*32 + i*16 + hi*4;
            #pragma unroll
            for (int rg = 0; rg < 4; ++rg)
                AB[(size_t)(rbase + rg) * 1536 + gc] = acc[i][j][rg] + bv;
        }
    }
}

// ---------------------------------------------------------------------------
// G4: pair[b,i,j] = (j<i) ? sum_h relu(AI+BJ)*W2[h] + b2 : 0
// Full 8x8 tile grid; upper tiles write zeros (no memset needed).
// AB = [512][1536] fp32, AI at +0 (b1 folded), BJ at +768.
// ---------------------------------------------------------------------------
__global__ __launch_bounds__(256) void k_pair(
    const float* __restrict__ AB, const float* __restrict__ W2,
    const float* __restrict__ b2, float* __restrict__ pair)
{
    const int tid = threadIdx.x;
    const int bx = blockIdx.x & 7, by = blockIdx.x >> 3;
    const int bz = blockIdx.y;

    const int tx = tid & 15, ty = tid >> 4;
    const int i = by * 16 + ty, j = bx * 16 + tx;
    float* outp = pair + ((size_t)bz * NSPAN + i) * NSPAN + j;

    if (bx > by) { *outp = 0.f; return; }   // strictly-upper tile: all zero

    __shared__ __align__(16) float Ais[16][68];
    __shared__ __align__(16) float Bjs[16][68];
    __shared__ __align__(16) float w2s[768];
    for (int q = tid; q < 768; q += 256) w2s[q] = W2[q];

    const int sr = tid >> 4, sc = (tid & 15) << 2;
    float acc = 0.f;

    for (int ch = 0; ch < 12; ++ch) {
        __syncthreads();
        *(float4*)&Ais[sr][sc] =
            *(const float4*)(AB + ((size_t)bz*NSPAN + by*16 + sr)*1536 + ch*64 + sc);
        *(float4*)&Bjs[sr][sc] =
            *(const float4*)(AB + ((size_t)bz*NSPAN + bx*16 + sr)*1536 + 768 + ch*64 + sc);
        __syncthreads();
        #pragma unroll
        for (int hq = 0; hq < 16; ++hq) {
            float4 a = *(const float4*)&Ais[ty][hq << 2];
            float4 b = *(const float4*)&Bjs[tx][hq << 2];
            float4 wv = *(const float4*)&w2s[ch*64 + (hq << 2)];
            acc = fmaf(fmaxf(a.x + b.x, 0.f), wv.x, acc);
            acc = fmaf(fmaxf(a.y + b.y, 0.f), wv.y, acc);
            acc = fmaf(fmaxf(a.z + b.z, 0.f), wv.z, acc);
            acc = fmaf(fmaxf(a.w + b.w, 0.f), wv.w, acc);
        }
    }
    *outp = (j < i) ? (acc + b2[0]) : 0.f;
}

// ---------------------------------------------------------------------------
extern "C" void kernel_launch(void* const* d_in, const int* in_sizes, int n_in,
                              void* d_out, int out_size, void* d_ws, size_t ws_size,
                              hipStream_t stream)
{
    const float* seq    = (const float*)d_in[0];
    const int*   starts = (const int*)  d_in[1];
    const int*   ends   = (const int*)  d_in[2];
    const float* Ws     = (const float*)d_in[3];
    const float* bs     = (const float*)d_in[4];
    const float* We     = (const float*)d_in[5];
    const float* be     = (const float*)d_in[6];
    const float* wemb   = (const float*)d_in[7];
    const float* Wout   = (const float*)d_in[8];
    const float* bout   = (const float*)d_in[9];
    const float* Wm     = (const float*)d_in[10];
    const float* bment  = (const float*)d_in[11];
    const float* W1     = (const float*)d_in[12];
    const float* b1     = (const float*)d_in[13];
    const float* W2     = (const float*)d_in[14];
    const float* b2     = (const float*)d_in[15];

    float* ws = (float*)d_ws;
    float* AB    = ws;                          // 512*1536 fp32
    short* Xg    = (short*)(ws + 786432);       // 1024*768 bf16
    short* Xcat  = (short*)(ws + 1179648);      // 512*1600 bf16
    short* SR    = (short*)(ws + 1589248);      // 512*768  bf16
    short* WtSE  = (short*)(ws + 1785856);      // 1536*768 bf16
    short* WtAB  = (short*)(ws + 2375680);      // 1536*768 bf16
    short* WtOut = (short*)(ws + 2965504);      // 768*1600 bf16

    float* out_mention = (float*)d_out;         // 512
    float* out_pair    = (float*)d_out + 512;   // 4*128*128

    hipLaunchKernelGGL(k_prep, dim3(3888), dim3(256), 0, stream,
                       seq, starts, ends, Ws, We, W1, Wout, wemb,
                       WtSE, WtAB, WtOut, Xg, Xcat);
    hipLaunchKernelGGL(k_g1, dim3(16, 24), dim3(128), 0, stream,
                       Xg, WtSE, bs, be, Xcat);
    hipLaunchKernelGGL(k_g2, dim3(16, 12), dim3(128), 0, stream,
                       Xcat, WtOut, bout, SR);
    hipLaunchKernelGGL(k_g3, dim3(16, 25), dim3(128), 0, stream,
                       SR, WtAB, b1, Wm, bment, AB, out_mention);
    hipLaunchKernelGGL(k_pair, dim3(64, 4), dim3(256), 0, stream,
                       AB, W2, b2, out_pair);
}